// Round 3
// baseline (9977.746 us; speedup 1.0000x reference)
//
#include <hip/hip_runtime.h>
#include <cstdint>
#include <cstddef>

#define NB 32       // batch
#define NT 512      // time steps
#define ND 512      // input dim D
#define NH 1024     // hidden H
#define NC4 4608    // 4H + 4*HH (fused GEMM N)
#define NBLK 64     // main-kernel grid (16 h-cols per block)

typedef short sh8 __attribute__((ext_vector_type(8)));   // 8 bf16 (raw bits)
typedef float f4  __attribute__((ext_vector_type(4)));
typedef unsigned int u4 __attribute__((ext_vector_type(4)));

__device__ __forceinline__ unsigned short f2bf(float x) {
  union { float f; unsigned u; } v; v.f = x;
  unsigned r = v.u + 0x7FFFu + ((v.u >> 16) & 1u);   // RNE
  return (unsigned short)(r >> 16);
}
__device__ __forceinline__ float bf2f(unsigned short b) {
  union { unsigned u; float f; } v; v.u = ((unsigned)b) << 16; return v.f;
}
__device__ __forceinline__ float blo(unsigned w) { union { unsigned u; float f; } v; v.u = w << 16; return v.f; }
__device__ __forceinline__ float bhi(unsigned w) { union { unsigned u; float f; } v; v.u = w & 0xFFFF0000u; return v.f; }

// ---------------------------------------------------------------------------
// prep: hyper gate weights -> bf16 transposed [4][j=128][k=128];
//       pz weights -> fp32 [3][c=16][k=128]; zero h buf0; zero 64 flag lines
// ---------------------------------------------------------------------------
__global__ __launch_bounds__(256) void k_prep(
    const float* __restrict__ wih, const float* __restrict__ wgh,
    const float* __restrict__ wfh, const float* __restrict__ woh,
    const float* __restrict__ pzx, const float* __restrict__ pzh,
    const float* __restrict__ pzb,
    unsigned short* __restrict__ whht, float* __restrict__ pzt,
    unsigned int* __restrict__ hbuf32, int* __restrict__ flags)
{
  int idx = blockIdx.x * 256 + threadIdx.x;
  if (idx < 65536) {  // 4*128*128
    int g = idx >> 14, r = idx & 16383, j = r >> 7, k = r & 127;
    const float* w = (g == 0) ? wih : (g == 1) ? wgh : (g == 2) ? wfh : woh;
    whht[idx] = f2bf(w[k * 128 + j]);
  }
  if (idx < 6144) {   // 3*16*128
    int r = idx & 2047, c = r >> 7, k = r & 127;
    int kind = idx >> 11;
    const float* p = (kind == 0) ? pzx : (kind == 1) ? pzh : pzb;
    pzt[idx] = p[k * 16 + c];
    (void)c; (void)k;
  }
  if (idx < 16384)   // zero buf0 (32*1024 bf16) via MALL so step-0 reads see it
    __hip_atomic_store(hbuf32 + idx, 0u, __ATOMIC_RELAXED, __HIP_MEMORY_SCOPE_AGENT);
  if (idx < 2048)
    __hip_atomic_store(flags + idx, 0, __ATOMIC_RELAXED, __HIP_MEMORY_SCOPE_AGENT);
}

// ---------------------------------------------------------------------------
// transpose Wcat -> bf16 [n=4608][k=512]: n<4096 from Wm[:512], else Wi/g/f/o_x
// ---------------------------------------------------------------------------
__global__ __launch_bounds__(256) void k_twcat(
    const float* __restrict__ wm, const float* __restrict__ wix,
    const float* __restrict__ wgx, const float* __restrict__ wfx,
    const float* __restrict__ wox, unsigned short* __restrict__ dst)
{
  __shared__ float tile[32][33];
  int bx = blockIdx.x % 144, by = blockIdx.x / 144;
  int n0 = bx * 32, k0 = by * 32;
  int tx = threadIdx.x & 31, ty = threadIdx.x >> 5;
  #pragma unroll
  for (int i = 0; i < 4; i++) {
    int k = k0 + ty + i * 8, n = n0 + tx;
    float v;
    if (n < 4096) v = wm[(size_t)k * 4096 + n];
    else {
      int nn = n - 4096, g = nn >> 7, j = nn & 127;
      const float* w = (g == 0) ? wix : (g == 1) ? wgx : (g == 2) ? wfx : wox;
      v = w[k * 128 + j];
    }
    tile[ty + i * 8][tx] = v;
  }
  __syncthreads();
  #pragma unroll
  for (int i = 0; i < 4; i++)
    dst[(size_t)(n0 + ty + i * 8) * 512 + k0 + tx] = f2bf(tile[tx][ty + i * 8]);
}

// transpose Wm[512:] -> bf16 [n=4096][k=1024]
__global__ __launch_bounds__(256) void k_twmh(
    const float* __restrict__ wm, unsigned short* __restrict__ dst)
{
  __shared__ float tile[32][33];
  int bx = blockIdx.x % 128, by = blockIdx.x / 128;
  int n0 = bx * 32, k0 = by * 32;
  int tx = threadIdx.x & 31, ty = threadIdx.x >> 5;
  #pragma unroll
  for (int i = 0; i < 4; i++)
    tile[ty + i * 8][tx] = wm[(size_t)(512 + k0 + ty + i * 8) * 4096 + n0 + tx];
  __syncthreads();
  #pragma unroll
  for (int i = 0; i < 4; i++)
    dst[(size_t)(n0 + ty + i * 8) * 1024 + k0 + tx] = f2bf(tile[tx][ty + i * 8]);
}

// ---------------------------------------------------------------------------
// Precompute GEMM: PreAll[t*32+b][n] = bf16( x[b*512+t][:] @ Wcat[:,n] )
// M=16384 K=512 N=4608, bf16 MFMA 16x16x32, 128x128 tile, 4 waves (2x2 of 64x64)
// ---------------------------------------------------------------------------
__global__ __launch_bounds__(256) void k_gemm(
    const float* __restrict__ x, const unsigned short* __restrict__ wt,
    unsigned short* __restrict__ preall)
{
  __shared__ unsigned short la[4096];  // [128 rows][32 k], XOR-swizzled 16B granules
  __shared__ unsigned short lb[4096];
  int bid = blockIdx.x;
  int mb = bid % 128, nb = bid / 128;
  int m0 = mb * 128, n0 = nb * 128;
  int tid = threadIdx.x;
  int lane = tid & 63, wid = tid >> 6;
  int wr = (wid >> 1) * 64, wc = (wid & 1) * 64;
  f4 acc[4][4] = {};
  for (int kt = 0; kt < 16; kt++) {
    int k0 = kt * 32;
    __syncthreads();
    {   // stage A (fp32 -> bf16): 2 threads/row, 16 floats each
      int r = tid >> 1, kh = (tid & 1) * 16;
      const float4* srcA = (const float4*)(x + (size_t)(m0 + r) * 512 + k0 + kh);
      unsigned pk[8];
      #pragma unroll
      for (int q = 0; q < 4; q++) {
        float4 f = srcA[q];
        pk[q * 2]     = (unsigned)f2bf(f.x) | ((unsigned)f2bf(f.y) << 16);
        pk[q * 2 + 1] = (unsigned)f2bf(f.z) | ((unsigned)f2bf(f.w) << 16);
      }
      int base = r * 64 + kh * 2;
      u4 v0 = {pk[0], pk[1], pk[2], pk[3]}, v1 = {pk[4], pk[5], pk[6], pk[7]};
      *(u4*)((char*)la + ((base)      ^ ((r & 7) << 4))) = v0;
      *(u4*)((char*)la + ((base + 16) ^ ((r & 7) << 4))) = v1;
    }
    {   // stage B (already bf16): 2 threads/row, 16 bf16 each
      int r = tid >> 1, kh = (tid & 1) * 16;
      const u4* srcB = (const u4*)(wt + (size_t)(n0 + r) * 512 + k0 + kh);
      u4 v0 = srcB[0], v1 = srcB[1];
      int base = r * 64 + kh * 2;
      *(u4*)((char*)lb + ((base)      ^ ((r & 7) << 4))) = v0;
      *(u4*)((char*)lb + ((base + 16) ^ ((r & 7) << 4))) = v1;
    }
    __syncthreads();
    int fo = (lane >> 4) * 16;
    sh8 af[4], bfr[4];
    #pragma unroll
    for (int mt = 0; mt < 4; mt++) {
      int r = wr + mt * 16 + (lane & 15);
      af[mt] = *(sh8*)((char*)la + ((r * 64 + fo) ^ ((r & 7) << 4)));
    }
    #pragma unroll
    for (int nt = 0; nt < 4; nt++) {
      int r = wc + nt * 16 + (lane & 15);
      bfr[nt] = *(sh8*)((char*)lb + ((r * 64 + fo) ^ ((r & 7) << 4)));
    }
    #pragma unroll
    for (int mt = 0; mt < 4; mt++)
      #pragma unroll
      for (int nt = 0; nt < 4; nt++)
        acc[mt][nt] = __builtin_amdgcn_mfma_f32_16x16x32_bf16(af[mt], bfr[nt], acc[mt][nt], 0, 0, 0);
  }
  // C write: row m -> (b=m>>9, t=m&511) -> PreAll row t*32+b, bf16
  #pragma unroll
  for (int mt = 0; mt < 4; mt++)
    #pragma unroll
    for (int nt = 0; nt < 4; nt++) {
      f4 a = acc[mt][nt];
      #pragma unroll
      for (int rr = 0; rr < 4; rr++) {
        int m = m0 + wr + mt * 16 + (lane >> 4) * 4 + rr;
        int n = n0 + wc + nt * 16 + (lane & 15);
        int b = m >> 9, t = m & 511;
        preall[(size_t)(t * 32 + b) * NC4 + n] = f2bf(a[rr]);
      }
    }
}

// ---------------------------------------------------------------------------
// Hyper chain: 1 block per batch row, 512 threads = (gate g, j).
// Gate weights live in VGPRs (bf16). Produces z[t][b][48] fp32.
// ---------------------------------------------------------------------------
__global__ __launch_bounds__(512) void k_hyper(
    const unsigned short* __restrict__ preall,  // xproj at cols 4096+
    const unsigned short* __restrict__ whht,    // [4][128][128] bf16
    const float* __restrict__ pzt,              // [3][16][128] fp32
    const float* __restrict__ bi, const float* __restrict__ bg,
    const float* __restrict__ bff, const float* __restrict__ bo,
    const float* __restrict__ lnig, const float* __restrict__ lnib,
    const float* __restrict__ lngg, const float* __restrict__ lngb,
    const float* __restrict__ lnfg, const float* __restrict__ lnfb,
    const float* __restrict__ lnog, const float* __restrict__ lnob,
    const float* __restrict__ lncg, const float* __restrict__ lncb,
    const float* __restrict__ pzxb, const float* __restrict__ pzhb,
    const float* __restrict__ pzbb,
    float* __restrict__ zout)
{
  const int b = blockIdx.x;
  const int tid = threadIdx.x;
  const int g = tid >> 7, j = tid & 127;
  __shared__ __align__(16) float hh[128];
  __shared__ __align__(16) float ch[128];
  __shared__ float act[4][128];
  __shared__ float red[20];
  __shared__ __align__(16) float pzl[48 * 132];  // padded rows (132) -> conflict-free

  u4 wreg[16];  // 128 bf16 weights for column (g,j)
  {
    const u4* wsrc = (const u4*)(whht + (size_t)(g * 128 + j) * 128);
    #pragma unroll
    for (int i = 0; i < 16; i++) wreg[i] = wsrc[i];
  }
  for (int i = tid; i < 6144; i += 512)
    pzl[(i >> 7) * 132 + (i & 127)] = pzt[i];

  float bias = ((g == 0) ? bi : (g == 1) ? bg : (g == 2) ? bff : bo)[j];
  float lgam = ((g == 0) ? lnig : (g == 1) ? lngg : (g == 2) ? lnfg : lnog)[j];
  float lbet = ((g == 0) ? lnib : (g == 1) ? lngb : (g == 2) ? lnfb : lnob)[j];
  float lcg = 0.f, lcb = 0.f;
  if (tid < 128) { lcg = lncg[tid]; lcb = lncb[tid]; hh[tid] = 0.f; ch[tid] = 0.f; }
  float zbias = 0.f;
  if (tid < 48) {
    int kind = tid >> 4, c = tid & 15;
    zbias = ((kind == 0) ? pzxb : (kind == 1) ? pzhb : pzbb)[c];
  }
  __syncthreads();

  const f4* h4 = (const f4*)hh;
  for (int t = 0; t < NT; t++) {
    float xp = bf2f(preall[(size_t)(t * 32 + b) * NC4 + 4096 + tid]);
    float s = bias;
    #pragma unroll
    for (int i = 0; i < 16; i++) {
      u4 w = wreg[i];
      f4 ha = h4[2 * i], hb = h4[2 * i + 1];
      s += blo(w.x) * ha[0] + bhi(w.x) * ha[1] + blo(w.y) * ha[2] + bhi(w.y) * ha[3]
         + blo(w.z) * hb[0] + bhi(w.z) * hb[1] + blo(w.w) * hb[2] + bhi(w.w) * hb[3];
    }
    s += xp;
    float s1 = s, s2 = s * s;
    #pragma unroll
    for (int m = 1; m < 64; m <<= 1) { s1 += __shfl_xor(s1, m); s2 += __shfl_xor(s2, m); }
    if ((tid & 63) == 0) { int w = tid >> 6; red[w * 2] = s1; red[w * 2 + 1] = s2; }
    __syncthreads();
    float sum = red[4 * g] + red[4 * g + 2], sq = red[4 * g + 1] + red[4 * g + 3];
    float mean = sum * 0.0078125f;
    float var = sq * 0.0078125f - mean * mean;
    float xn = (s - mean) * rsqrtf(var + 1e-5f) * lgam + lbet;
    float a = (g == 1) ? tanhf(xn) : 1.f / (1.f + __expf(-xn));
    act[g][j] = a;
    __syncthreads();
    if (tid < 128) {
      float cn = act[2][tid] * ch[tid] + act[0][tid] * act[1][tid];
      ch[tid] = cn;
      float c1 = cn, c2 = cn * cn;
      #pragma unroll
      for (int m = 1; m < 64; m <<= 1) { c1 += __shfl_xor(c1, m); c2 += __shfl_xor(c2, m); }
      if ((tid & 63) == 0) { int w = tid >> 6; red[16 + w * 2] = c1; red[16 + w * 2 + 1] = c2; }
    }
    __syncthreads();
    if (tid < 128) {
      float sum2 = red[16] + red[18], sq2 = red[17] + red[19];
      float mean2 = sum2 * 0.0078125f, var2 = sq2 * 0.0078125f - mean2 * mean2;
      float cn = ch[tid];
      hh[tid] = act[3][tid] * tanhf((cn - mean2) * rsqrtf(var2 + 1e-5f) * lcg + lcb);
    }
    __syncthreads();
    if (tid < 48) {   // z = hh_new @ pz*_w + pz*_b
      const f4* pr = (const f4*)(pzl + tid * 132);
      float zv = zbias;
      #pragma unroll 8
      for (int q = 0; q < 32; q++) {
        f4 p = pr[q], hv = h4[q];
        zv += p[0] * hv[0] + p[1] * hv[1] + p[2] * hv[2] + p[3] * hv[3];
      }
      zout[(size_t)(t * 32 + b) * 48 + tid] = zv;
    }
    __syncthreads();
  }
}

// ---------------------------------------------------------------------------
// Main recurrence: persistent 64 blocks x 256 thr. Block owns 16 h-cols
// (64 gate-cols). W slice (128KB bf16, swizzled) in LDS.
// Sync: distributed flags, ALL cross-block traffic (h, flags) moves through
// MALL via relaxed agent-scope atomics (L2-bypass) -> NO threadfence, NO
// buffer_wbl2/buffer_inv in the loop. out[] stays ordinary cached stores.
// ---------------------------------------------------------------------------
__global__ __launch_bounds__(256) void k_main(
    const unsigned short* __restrict__ preall,
    const unsigned short* __restrict__ wmht,
    const float* __restrict__ zbuf,
    const float* __restrict__ pdx, const float* __restrict__ pdh,
    const float* __restrict__ pbw, const float* __restrict__ pbb,
    unsigned int* __restrict__ hbuf32,    // [2][32][512] u32 (bf16 pairs) ping-pong
    float* __restrict__ out,
    int* __restrict__ flags)
{
  __shared__ unsigned short wlds[64 * 1024];   // [n=64][k=1024] bf16, XOR-swizzled (128KB)
  __shared__ float red[2][32][68];             // [K-half][b][n] partials (17.4KB)
  __shared__ __align__(16) float zl[32 * 48];  // z(t) staging (6KB)
  __shared__ float clds[512];                  // c state: [b][jo]
  __shared__ unsigned short hl16[32][16];      // h(t+1) slice staging (1KB)
  __shared__ float pdl[3][4][16];
  __shared__ float pbbl[16];

  const int tid = threadIdx.x;
  const int lane = tid & 63, wid = tid >> 6;
  const int jh0 = blockIdx.x * 16;
  const int jw0 = blockIdx.x * 8;              // u32 col offset in hbuf32

  {   // stage weight slice once: n = g*16+jo -> wmht row g*NH + jh0 + jo
    int n = tid >> 2, kc = (tid & 3) * 256;
    int g = n >> 4, jo = n & 15;
    const unsigned short* src = wmht + (size_t)(g * NH + jh0 + jo) * NH + kc;
    #pragma unroll
    for (int i = 0; i < 32; i++) {
      sh8 v = *(const sh8*)(src + i * 8);
      int byte = n * 2048 + (kc + i * 8) * 2;
      *(sh8*)((char*)wlds + (byte ^ ((n & 7) << 4))) = v;
    }
  }
  clds[tid] = 0.f; clds[tid + 256] = 0.f;
  if (tid < 192) {
    int kind = tid >> 6, e = (tid >> 4) & 3, jo = tid & 15;
    const float* p = (kind == 0) ? pdx : (kind == 1) ? pdh : pbw;
    pdl[kind][e][jo] = p[e * NH + jh0 + jo];
  }
  if (tid < 16) pbbl[tid] = pbb[jh0 + tid];
  __syncthreads();

  const int bq = tid >> 3;    // combine row b: 0..31
  const int jo2 = tid & 7;    // combine col pair base: jo2, jo2+8

  for (int t = 0; t < NT; t++) {
    // ---- prefetch Wx + z into regs (independent of h(t), cached reads) ---
    float wx[2][4];
    {
      const unsigned short* ps = preall + (size_t)(t * NB + bq) * NC4 + jh0;
      #pragma unroll
      for (int g = 0; g < 4; g++) {
        wx[0][g] = bf2f(ps[g * NH + jo2]);
        wx[1][g] = bf2f(ps[g * NH + jo2 + 8]);
      }
    }
    if (tid < 192) {   // stage z(t); zl free since previous combine done
      const f4* zs = (const f4*)(zbuf + (size_t)t * NB * 48) + tid * 2;
      f4 a = zs[0], bz = zs[1];
      f4* zd = (f4*)zl + tid * 2;
      zd[0] = a; zd[1] = bz;
    }
    // ---- wait for h(t): relaxed agent polls (MALL reads, no inv) ---------
    if (wid == 0) {
      for (;;) {
        int v = __hip_atomic_load(flags + lane * 32, __ATOMIC_RELAXED,
                                  __HIP_MEMORY_SCOPE_AGENT);
        if (__all(v >= t)) break;
      }
    }
    __syncthreads();
    asm volatile("" ::: "memory");
    const unsigned int* hc32 = hbuf32 + (t & 1) * (NB * NH / 2);
    // ---- W_h: wave = (kh = K-half, nh = N-half); A via MALL atomic loads -
    {
      const int kh = wid >> 1, nh = wid & 1;
      const int koff = (lane >> 4) * 8;            // bf16 offset within 32-col slab
      const int col = lane & 15;
      f4 acc[2][2] = {};
      #pragma unroll
      for (int ks = 0; ks < 16; ks++) {
        int kb = kh * 512 + ks * 32 + koff;        // bf16 K index
        int u0 = col * 512 + (kb >> 1);            // u32 index, row col
        int u1 = (16 + col) * 512 + (kb >> 1);     // u32 index, row 16+col
        union { u4 u; sh8 s; } a0v, a1v;
        #pragma unroll
        for (int q = 0; q < 4; q++) {
          a0v.u[q] = __hip_atomic_load((unsigned int*)hc32 + u0 + q,
                                       __ATOMIC_RELAXED, __HIP_MEMORY_SCOPE_AGENT);
          a1v.u[q] = __hip_atomic_load((unsigned int*)hc32 + u1 + q,
                                       __ATOMIC_RELAXED, __HIP_MEMORY_SCOPE_AGENT);
        }
        int n0 = nh * 32 + col, n1 = nh * 32 + 16 + col;
        sh8 b0 = *(sh8*)((char*)wlds + ((n0 * 2048 + kb * 2) ^ ((n0 & 7) << 4)));
        sh8 b1 = *(sh8*)((char*)wlds + ((n1 * 2048 + kb * 2) ^ ((n1 & 7) << 4)));
        acc[0][0] = __builtin_amdgcn_mfma_f32_16x16x32_bf16(a0v.s, b0, acc[0][0], 0, 0, 0);
        acc[0][1] = __builtin_amdgcn_mfma_f32_16x16x32_bf16(a0v.s, b1, acc[0][1], 0, 0, 0);
        acc[1][0] = __builtin_amdgcn_mfma_f32_16x16x32_bf16(a1v.s, b0, acc[1][0], 0, 0, 0);
        acc[1][1] = __builtin_amdgcn_mfma_f32_16x16x32_bf16(a1v.s, b1, acc[1][1], 0, 0, 0);
      }
      int r0 = (lane >> 4) * 4;
      #pragma unroll
      for (int mt = 0; mt < 2; mt++)
        #pragma unroll
        for (int nt = 0; nt < 2; nt++)
          #pragma unroll
          for (int rr = 0; rr < 4; rr++)
            red[kh][mt * 16 + r0 + rr][nh * 32 + nt * 16 + col] = acc[mt][nt][rr];
    }
    __syncthreads();
    // ---- combine: thread (bq, jo2) handles jo2 and jo2+8 -----------------
    const float* zb_ = zl + bq * 48;
    #pragma unroll
    for (int half = 0; half < 2; half++) {
      int jo = jo2 + half * 8;
      float gv[4];
      #pragma unroll
      for (int g = 0; g < 4; g++) {
        float wh = red[0][bq][g * 16 + jo] + red[1][bq][g * 16 + jo];
        float dxv = 0.f, dhv = 0.f, bdv = pbbl[jo];
        #pragma unroll
        for (int e = 0; e < 4; e++) {
          dxv += zb_[g * 4 + e]      * pdl[0][e][jo];
          dhv += zb_[16 + g * 4 + e] * pdl[1][e][jo];
          bdv += zb_[32 + g * 4 + e] * pdl[2][e][jo];
        }
        gv[g] = wx[half][g] * dxv + wh * dhv + bdv;
      }
      float iv = 1.f / (1.f + __expf(-gv[0]));
      float fv = 1.f / (1.f + __expf(-gv[1]));
      float ov = 1.f / (1.f + __expf(-gv[2]));
      float gg = tanhf(gv[3]);
      int ci = bq * 16 + jo;
      float cn = fv * clds[ci] + iv * gg;
      clds[ci] = cn;
      float hn = ov * tanhf(cn);
      out[(size_t)(bq * NT + t) * NH + jh0 + jo] = hn;   // ordinary cached store
      hl16[bq][jo] = f2bf(hn);
      if (t == NT - 1) {
        out[(size_t)NB * NT * NH + bq * NH + jh0 + jo] = hn;
        out[(size_t)NB * NT * NH + NB * NH + bq * NH + jh0 + jo] = cn;
      }
    }
    __syncthreads();   // hl16 complete
    // ---- publish h(t+1): 256 x 4B MALL stores, drain, relaxed flag -------
    {
      int b = tid >> 3, p = tid & 7;
      unsigned val = (unsigned)hl16[b][2 * p] | ((unsigned)hl16[b][2 * p + 1] << 16);
      __hip_atomic_store(hbuf32 + ((t + 1) & 1) * (NB * NH / 2) + b * 512 + jw0 + p,
                         val, __ATOMIC_RELAXED, __HIP_MEMORY_SCOPE_AGENT);
    }
    asm volatile("s_waitcnt vmcnt(0)" ::: "memory");
    __syncthreads();   // all waves drained
    if (tid == 0)
      __hip_atomic_store(flags + blockIdx.x * 32, t + 1, __ATOMIC_RELAXED,
                         __HIP_MEMORY_SCOPE_AGENT);
  }
}

// ---------------------------------------------------------------------------
extern "C" void kernel_launch(void* const* d_in, const int* in_sizes, int n_in,
                              void* d_out, int out_size, void* d_ws, size_t ws_size,
                              hipStream_t stream) {
  (void)in_sizes; (void)n_in; (void)out_size;
  const float* x    = (const float*)d_in[0];
  const float* Wm   = (const float*)d_in[1];
  const float* Wih  = (const float*)d_in[2];
  const float* Wix  = (const float*)d_in[3];
  const float* bi   = (const float*)d_in[4];
  const float* Wgh  = (const float*)d_in[5];
  const float* Wgx  = (const float*)d_in[6];
  const float* bg   = (const float*)d_in[7];
  const float* Wfh  = (const float*)d_in[8];
  const float* Wfx  = (const float*)d_in[9];
  const float* bfp  = (const float*)d_in[10];
  const float* Woh  = (const float*)d_in[11];
  const float* Wox  = (const float*)d_in[12];
  const float* bo   = (const float*)d_in[13];
  const float* lnig = (const float*)d_in[14];
  const float* lnib = (const float*)d_in[15];
  const float* lngg = (const float*)d_in[16];
  const float* lngb = (const float*)d_in[17];
  const float* lnfg = (const float*)d_in[18];
  const float* lnfb = (const float*)d_in[19];
  const float* lnog = (const float*)d_in[20];
  const float* lnob = (const float*)d_in[21];
  const float* lncg = (const float*)d_in[22];
  const float* lncb = (const float*)d_in[23];
  const float* pzxw = (const float*)d_in[24];
  const float* pzxb = (const float*)d_in[25];
  const float* pzhw = (const float*)d_in[26];
  const float* pzhb = (const float*)d_in[27];
  const float* pzbw = (const float*)d_in[28];
  const float* pzbb = (const float*)d_in[29];
  const float* pdx  = (const float*)d_in[30];
  const float* pdh  = (const float*)d_in[31];
  const float* pbw  = (const float*)d_in[32];
  const float* pbb  = (const float*)d_in[33];
  float* out = (float*)d_out;

  char* ws = (char*)d_ws;
  size_t off = 0;
  auto alloc = [&](size_t bytes) {
    char* p = ws + off; off += (bytes + 255) & ~(size_t)255; return p;
  };
  unsigned short* preall = (unsigned short*)alloc((size_t)16384 * NC4 * 2);
  unsigned short* wcat   = (unsigned short*)alloc((size_t)NC4 * 512 * 2);
  unsigned short* wmht   = (unsigned short*)alloc((size_t)4096 * 1024 * 2);
  unsigned short* whht   = (unsigned short*)alloc((size_t)4 * 128 * 128 * 2);
  float* pzt             = (float*)alloc((size_t)3 * 16 * 128 * 4);
  float* zbuf            = (float*)alloc((size_t)NT * NB * 48 * 4);
  unsigned int* hbuf32   = (unsigned int*)alloc((size_t)2 * NB * NH * 2);
  int* flags             = (int*)alloc((size_t)64 * 32 * 4);
  if (off > ws_size) return;  // ws too small: leave output untouched (diagnosable)

  k_prep<<<256, 256, 0, stream>>>(Wih, Wgh, Wfh, Woh, pzxw, pzhw, pzbw, whht, pzt, hbuf32, flags);
  k_twcat<<<2304, 256, 0, stream>>>(Wm, Wix, Wgx, Wfx, Wox, wcat);
  k_twmh<<<4096, 256, 0, stream>>>(Wm, wmht);
  k_gemm<<<4608, 256, 0, stream>>>(x, wcat, preall);
  k_hyper<<<32, 512, 0, stream>>>(preall, whht, pzt, bi, bg, bfp, bo,
      lnig, lnib, lngg, lngb, lnfg, lnfb, lnog, lnob, lncg, lncb,
      pzxb, pzhb, pzbb, zbuf);
  k_main<<<NBLK, 256, 0, stream>>>(preall, wmht, zbuf, pdx, pdh, pbw, pbb, hbuf32, out, flags);
}

// Round 4
// 5114.059 us; speedup vs baseline: 1.9510x; 1.9510x over previous
//
#include <hip/hip_runtime.h>
#include <cstdint>
#include <cstddef>

#define NB 32       // batch
#define NT 512      // time steps
#define ND 512      // input dim D
#define NH 1024     // hidden H
#define NC4 4608    // 4H + 4*HH (fused GEMM N)
#define NBLK 64     // main-kernel grid (16 h-cols per block)

typedef short sh8 __attribute__((ext_vector_type(8)));   // 8 bf16 (raw bits)
typedef float f4  __attribute__((ext_vector_type(4)));
typedef unsigned int u4 __attribute__((ext_vector_type(4)));

__device__ __forceinline__ unsigned short f2bf(float x) {
  union { float f; unsigned u; } v; v.f = x;
  unsigned r = v.u + 0x7FFFu + ((v.u >> 16) & 1u);   // RNE
  return (unsigned short)(r >> 16);
}
__device__ __forceinline__ float bf2f(unsigned short b) {
  union { unsigned u; float f; } v; v.u = ((unsigned)b) << 16; return v.f;
}
__device__ __forceinline__ float blo(unsigned w) { union { unsigned u; float f; } v; v.u = w << 16; return v.f; }
__device__ __forceinline__ float bhi(unsigned w) { union { unsigned u; float f; } v; v.u = w & 0xFFFF0000u; return v.f; }

// MALL-coherent 16B load: bypasses L1/L2 (sc0 sc1). MALL is memory-side ->
// always holds the latest cross-XCD data. Caller must s_waitcnt vmcnt before use.
#define LD16(dst, base, OFFSTR)                                         \
  asm volatile("global_load_dwordx4 %0, %1, off offset:" OFFSTR " sc0 sc1" \
               : "=v"(dst) : "v"(base))

// ---------------------------------------------------------------------------
// prep: hyper gate weights -> bf16 transposed [4][j=128][k=128];
//       pz weights -> fp32 [3][c=16][k=128]; zero h buf0; zero 64 flag lines
// ---------------------------------------------------------------------------
__global__ __launch_bounds__(256) void k_prep(
    const float* __restrict__ wih, const float* __restrict__ wgh,
    const float* __restrict__ wfh, const float* __restrict__ woh,
    const float* __restrict__ pzx, const float* __restrict__ pzh,
    const float* __restrict__ pzb,
    unsigned short* __restrict__ whht, float* __restrict__ pzt,
    unsigned int* __restrict__ hbuf32, int* __restrict__ flags)
{
  int idx = blockIdx.x * 256 + threadIdx.x;
  if (idx < 65536) {  // 4*128*128
    int g = idx >> 14, r = idx & 16383, j = r >> 7, k = r & 127;
    const float* w = (g == 0) ? wih : (g == 1) ? wgh : (g == 2) ? wfh : woh;
    whht[idx] = f2bf(w[k * 128 + j]);
  }
  if (idx < 6144) {   // 3*16*128
    int r = idx & 2047, c = r >> 7, k = r & 127;
    int kind = idx >> 11;
    const float* p = (kind == 0) ? pzx : (kind == 1) ? pzh : pzb;
    pzt[idx] = p[k * 16 + c];
    (void)c; (void)k;
  }
  if (idx < 16384)   // zero buf0 (32*1024 bf16) via MALL so bypass-reads see it
    __hip_atomic_store(hbuf32 + idx, 0u, __ATOMIC_RELAXED, __HIP_MEMORY_SCOPE_AGENT);
  if (idx < 2048)
    __hip_atomic_store(flags + idx, 0, __ATOMIC_RELAXED, __HIP_MEMORY_SCOPE_AGENT);
}

// ---------------------------------------------------------------------------
// transpose Wcat -> bf16 [n=4608][k=512]: n<4096 from Wm[:512], else Wi/g/f/o_x
// ---------------------------------------------------------------------------
__global__ __launch_bounds__(256) void k_twcat(
    const float* __restrict__ wm, const float* __restrict__ wix,
    const float* __restrict__ wgx, const float* __restrict__ wfx,
    const float* __restrict__ wox, unsigned short* __restrict__ dst)
{
  __shared__ float tile[32][33];
  int bx = blockIdx.x % 144, by = blockIdx.x / 144;
  int n0 = bx * 32, k0 = by * 32;
  int tx = threadIdx.x & 31, ty = threadIdx.x >> 5;
  #pragma unroll
  for (int i = 0; i < 4; i++) {
    int k = k0 + ty + i * 8, n = n0 + tx;
    float v;
    if (n < 4096) v = wm[(size_t)k * 4096 + n];
    else {
      int nn = n - 4096, g = nn >> 7, j = nn & 127;
      const float* w = (g == 0) ? wix : (g == 1) ? wgx : (g == 2) ? wfx : wox;
      v = w[k * 128 + j];
    }
    tile[ty + i * 8][tx] = v;
  }
  __syncthreads();
  #pragma unroll
  for (int i = 0; i < 4; i++)
    dst[(size_t)(n0 + ty + i * 8) * 512 + k0 + tx] = f2bf(tile[tx][ty + i * 8]);
}

// transpose Wm[512:] -> bf16 [n=4096][k=1024]
__global__ __launch_bounds__(256) void k_twmh(
    const float* __restrict__ wm, unsigned short* __restrict__ dst)
{
  __shared__ float tile[32][33];
  int bx = blockIdx.x % 128, by = blockIdx.x / 128;
  int n0 = bx * 32, k0 = by * 32;
  int tx = threadIdx.x & 31, ty = threadIdx.x >> 5;
  #pragma unroll
  for (int i = 0; i < 4; i++)
    tile[ty + i * 8][tx] = wm[(size_t)(512 + k0 + ty + i * 8) * 4096 + n0 + tx];
  __syncthreads();
  #pragma unroll
  for (int i = 0; i < 4; i++)
    dst[(size_t)(n0 + ty + i * 8) * 1024 + k0 + tx] = f2bf(tile[tx][ty + i * 8]);
}

// ---------------------------------------------------------------------------
// Precompute GEMM: PreAll[t*32+b][n] = bf16( x[b*512+t][:] @ Wcat[:,n] )
// M=16384 K=512 N=4608, bf16 MFMA 16x16x32, 128x128 tile, 4 waves (2x2 of 64x64)
// ---------------------------------------------------------------------------
__global__ __launch_bounds__(256) void k_gemm(
    const float* __restrict__ x, const unsigned short* __restrict__ wt,
    unsigned short* __restrict__ preall)
{
  __shared__ unsigned short la[4096];  // [128 rows][32 k], XOR-swizzled 16B granules
  __shared__ unsigned short lb[4096];
  int bid = blockIdx.x;
  int mb = bid % 128, nb = bid / 128;
  int m0 = mb * 128, n0 = nb * 128;
  int tid = threadIdx.x;
  int lane = tid & 63, wid = tid >> 6;
  int wr = (wid >> 1) * 64, wc = (wid & 1) * 64;
  f4 acc[4][4] = {};
  for (int kt = 0; kt < 16; kt++) {
    int k0 = kt * 32;
    __syncthreads();
    {   // stage A (fp32 -> bf16): 2 threads/row, 16 floats each
      int r = tid >> 1, kh = (tid & 1) * 16;
      const float4* srcA = (const float4*)(x + (size_t)(m0 + r) * 512 + k0 + kh);
      unsigned pk[8];
      #pragma unroll
      for (int q = 0; q < 4; q++) {
        float4 f = srcA[q];
        pk[q * 2]     = (unsigned)f2bf(f.x) | ((unsigned)f2bf(f.y) << 16);
        pk[q * 2 + 1] = (unsigned)f2bf(f.z) | ((unsigned)f2bf(f.w) << 16);
      }
      int base = r * 64 + kh * 2;
      u4 v0 = {pk[0], pk[1], pk[2], pk[3]}, v1 = {pk[4], pk[5], pk[6], pk[7]};
      *(u4*)((char*)la + ((base)      ^ ((r & 7) << 4))) = v0;
      *(u4*)((char*)la + ((base + 16) ^ ((r & 7) << 4))) = v1;
    }
    {   // stage B (already bf16): 2 threads/row, 16 bf16 each
      int r = tid >> 1, kh = (tid & 1) * 16;
      const u4* srcB = (const u4*)(wt + (size_t)(n0 + r) * 512 + k0 + kh);
      u4 v0 = srcB[0], v1 = srcB[1];
      int base = r * 64 + kh * 2;
      *(u4*)((char*)lb + ((base)      ^ ((r & 7) << 4))) = v0;
      *(u4*)((char*)lb + ((base + 16) ^ ((r & 7) << 4))) = v1;
    }
    __syncthreads();
    int fo = (lane >> 4) * 16;
    sh8 af[4], bfr[4];
    #pragma unroll
    for (int mt = 0; mt < 4; mt++) {
      int r = wr + mt * 16 + (lane & 15);
      af[mt] = *(sh8*)((char*)la + ((r * 64 + fo) ^ ((r & 7) << 4)));
    }
    #pragma unroll
    for (int nt = 0; nt < 4; nt++) {
      int r = wc + nt * 16 + (lane & 15);
      bfr[nt] = *(sh8*)((char*)lb + ((r * 64 + fo) ^ ((r & 7) << 4)));
    }
    #pragma unroll
    for (int mt = 0; mt < 4; mt++)
      #pragma unroll
      for (int nt = 0; nt < 4; nt++)
        acc[mt][nt] = __builtin_amdgcn_mfma_f32_16x16x32_bf16(af[mt], bfr[nt], acc[mt][nt], 0, 0, 0);
  }
  // C write: row m -> (b=m>>9, t=m&511) -> PreAll row t*32+b, bf16
  #pragma unroll
  for (int mt = 0; mt < 4; mt++)
    #pragma unroll
    for (int nt = 0; nt < 4; nt++) {
      f4 a = acc[mt][nt];
      #pragma unroll
      for (int rr = 0; rr < 4; rr++) {
        int m = m0 + wr + mt * 16 + (lane >> 4) * 4 + rr;
        int n = n0 + wc + nt * 16 + (lane & 15);
        int b = m >> 9, t = m & 511;
        preall[(size_t)(t * 32 + b) * NC4 + n] = f2bf(a[rr]);
      }
    }
}

// ---------------------------------------------------------------------------
// Hyper chain: 1 block per batch row, 512 threads = (gate g, j).
// Gate weights live in VGPRs (bf16). Produces z[t][b][48] fp32.
// ---------------------------------------------------------------------------
__global__ __launch_bounds__(512) void k_hyper(
    const unsigned short* __restrict__ preall,  // xproj at cols 4096+
    const unsigned short* __restrict__ whht,    // [4][128][128] bf16
    const float* __restrict__ pzt,              // [3][16][128] fp32
    const float* __restrict__ bi, const float* __restrict__ bg,
    const float* __restrict__ bff, const float* __restrict__ bo,
    const float* __restrict__ lnig, const float* __restrict__ lnib,
    const float* __restrict__ lngg, const float* __restrict__ lngb,
    const float* __restrict__ lnfg, const float* __restrict__ lnfb,
    const float* __restrict__ lnog, const float* __restrict__ lnob,
    const float* __restrict__ lncg, const float* __restrict__ lncb,
    const float* __restrict__ pzxb, const float* __restrict__ pzhb,
    const float* __restrict__ pzbb,
    float* __restrict__ zout)
{
  const int b = blockIdx.x;
  const int tid = threadIdx.x;
  const int g = tid >> 7, j = tid & 127;
  __shared__ __align__(16) float hh[128];
  __shared__ __align__(16) float ch[128];
  __shared__ float act[4][128];
  __shared__ float red[20];
  __shared__ __align__(16) float pzl[48 * 132];  // padded rows (132) -> conflict-free

  u4 wreg[16];  // 128 bf16 weights for column (g,j)
  {
    const u4* wsrc = (const u4*)(whht + (size_t)(g * 128 + j) * 128);
    #pragma unroll
    for (int i = 0; i < 16; i++) wreg[i] = wsrc[i];
  }
  for (int i = tid; i < 6144; i += 512)
    pzl[(i >> 7) * 132 + (i & 127)] = pzt[i];

  float bias = ((g == 0) ? bi : (g == 1) ? bg : (g == 2) ? bff : bo)[j];
  float lgam = ((g == 0) ? lnig : (g == 1) ? lngg : (g == 2) ? lnfg : lnog)[j];
  float lbet = ((g == 0) ? lnib : (g == 1) ? lngb : (g == 2) ? lnfb : lnob)[j];
  float lcg = 0.f, lcb = 0.f;
  if (tid < 128) { lcg = lncg[tid]; lcb = lncb[tid]; hh[tid] = 0.f; ch[tid] = 0.f; }
  float zbias = 0.f;
  if (tid < 48) {
    int kind = tid >> 4, c = tid & 15;
    zbias = ((kind == 0) ? pzxb : (kind == 1) ? pzhb : pzbb)[c];
  }
  __syncthreads();

  const f4* h4 = (const f4*)hh;
  for (int t = 0; t < NT; t++) {
    float xp = bf2f(preall[(size_t)(t * 32 + b) * NC4 + 4096 + tid]);
    float s = bias;
    #pragma unroll
    for (int i = 0; i < 16; i++) {
      u4 w = wreg[i];
      f4 ha = h4[2 * i], hb = h4[2 * i + 1];
      s += blo(w.x) * ha[0] + bhi(w.x) * ha[1] + blo(w.y) * ha[2] + bhi(w.y) * ha[3]
         + blo(w.z) * hb[0] + bhi(w.z) * hb[1] + blo(w.w) * hb[2] + bhi(w.w) * hb[3];
    }
    s += xp;
    float s1 = s, s2 = s * s;
    #pragma unroll
    for (int m = 1; m < 64; m <<= 1) { s1 += __shfl_xor(s1, m); s2 += __shfl_xor(s2, m); }
    if ((tid & 63) == 0) { int w = tid >> 6; red[w * 2] = s1; red[w * 2 + 1] = s2; }
    __syncthreads();
    float sum = red[4 * g] + red[4 * g + 2], sq = red[4 * g + 1] + red[4 * g + 3];
    float mean = sum * 0.0078125f;
    float var = sq * 0.0078125f - mean * mean;
    float xn = (s - mean) * rsqrtf(var + 1e-5f) * lgam + lbet;
    float a = (g == 1) ? tanhf(xn) : 1.f / (1.f + __expf(-xn));
    act[g][j] = a;
    __syncthreads();
    if (tid < 128) {
      float cn = act[2][tid] * ch[tid] + act[0][tid] * act[1][tid];
      ch[tid] = cn;
      float c1 = cn, c2 = cn * cn;
      #pragma unroll
      for (int m = 1; m < 64; m <<= 1) { c1 += __shfl_xor(c1, m); c2 += __shfl_xor(c2, m); }
      if ((tid & 63) == 0) { int w = tid >> 6; red[16 + w * 2] = c1; red[16 + w * 2 + 1] = c2; }
    }
    __syncthreads();
    if (tid < 128) {
      float sum2 = red[16] + red[18], sq2 = red[17] + red[19];
      float mean2 = sum2 * 0.0078125f, var2 = sq2 * 0.0078125f - mean2 * mean2;
      float cn = ch[tid];
      hh[tid] = act[3][tid] * tanhf((cn - mean2) * rsqrtf(var2 + 1e-5f) * lcg + lcb);
    }
    __syncthreads();
    if (tid < 48) {   // z = hh_new @ pz*_w + pz*_b
      const f4* pr = (const f4*)(pzl + tid * 132);
      float zv = zbias;
      #pragma unroll 8
      for (int q = 0; q < 32; q++) {
        f4 p = pr[q], hv = h4[q];
        zv += p[0] * hv[0] + p[1] * hv[1] + p[2] * hv[2] + p[3] * hv[3];
      }
      zout[(size_t)(t * 32 + b) * 48 + tid] = zv;
    }
    __syncthreads();
  }
}

// ---------------------------------------------------------------------------
// Main recurrence: persistent 64 blocks x 256 thr. Block owns 16 h-cols
// (64 gate-cols). W slice (128KB bf16, swizzled) in LDS.
// Sync: distributed flags via relaxed agent atomics (4B each, cheap).
// h data: published via relaxed agent atomic dword stores (1KB/block/step),
// read via PLAIN VECTOR loads with sc0 sc1 (L1/L2 bypass -> MALL, which is
// memory-side and always current). No fences anywhere in the loop.
// ---------------------------------------------------------------------------
__global__ __launch_bounds__(256) void k_main(
    const unsigned short* __restrict__ preall,
    const unsigned short* __restrict__ wmht,
    const float* __restrict__ zbuf,
    const float* __restrict__ pdx, const float* __restrict__ pdh,
    const float* __restrict__ pbw, const float* __restrict__ pbb,
    unsigned int* __restrict__ hbuf32,    // [2][32][512] u32 (bf16 pairs) ping-pong
    float* __restrict__ out,
    int* __restrict__ flags)
{
  __shared__ unsigned short wlds[64 * 1024];   // [n=64][k=1024] bf16, XOR-swizzled (128KB)
  __shared__ float red[2][32][68];             // [K-half][b][n] partials (17.4KB)
  __shared__ __align__(16) float zl[32 * 48];  // z(t) staging (6KB)
  __shared__ float clds[512];                  // c state: [b][jo]
  __shared__ unsigned short hl16[32][16];      // h(t+1) slice staging (1KB)
  __shared__ float pdl[3][4][16];
  __shared__ float pbbl[16];

  const int tid = threadIdx.x;
  const int lane = tid & 63, wid = tid >> 6;
  const int jh0 = blockIdx.x * 16;
  const int jw0 = blockIdx.x * 8;              // u32 col offset in hbuf32

  {   // stage weight slice once: n = g*16+jo -> wmht row g*NH + jh0 + jo
    int n = tid >> 2, kc = (tid & 3) * 256;
    int g = n >> 4, jo = n & 15;
    const unsigned short* src = wmht + (size_t)(g * NH + jh0 + jo) * NH + kc;
    #pragma unroll
    for (int i = 0; i < 32; i++) {
      sh8 v = *(const sh8*)(src + i * 8);
      int byte = n * 2048 + (kc + i * 8) * 2;
      *(sh8*)((char*)wlds + (byte ^ ((n & 7) << 4))) = v;
    }
  }
  clds[tid] = 0.f; clds[tid + 256] = 0.f;
  if (tid < 192) {
    int kind = tid >> 6, e = (tid >> 4) & 3, jo = tid & 15;
    const float* p = (kind == 0) ? pdx : (kind == 1) ? pdh : pbw;
    pdl[kind][e][jo] = p[e * NH + jh0 + jo];
  }
  if (tid < 16) pbbl[tid] = pbb[jh0 + tid];
  __syncthreads();

  const int bq = tid >> 3;    // combine row b: 0..31
  const int jo2 = tid & 7;    // combine col pair base: jo2, jo2+8
  const int kh = wid >> 1, nh = wid & 1;
  const int col = lane & 15;

  for (int t = 0; t < NT; t++) {
    // ---- prefetch Wx + z into regs (independent of h(t), cached reads) ---
    float wx[2][4];
    {
      const unsigned short* ps = preall + (size_t)(t * NB + bq) * NC4 + jh0;
      #pragma unroll
      for (int g = 0; g < 4; g++) {
        wx[0][g] = bf2f(ps[g * NH + jo2]);
        wx[1][g] = bf2f(ps[g * NH + jo2 + 8]);
      }
    }
    if (tid < 192) {   // stage z(t); zl free since previous combine done
      const f4* zs = (const f4*)(zbuf + (size_t)t * NB * 48) + tid * 2;
      f4 a = zs[0], bz = zs[1];
      f4* zd = (f4*)zl + tid * 2;
      zd[0] = a; zd[1] = bz;
    }
    // ---- wait for h(t): wave0 polls flags (relaxed agent, strided lines) -
    if (wid == 0) {
      for (;;) {
        int v = (lane == blockIdx.x) ? t :
                __hip_atomic_load(flags + lane * 32, __ATOMIC_RELAXED,
                                  __HIP_MEMORY_SCOPE_AGENT);
        if (__all(v >= t)) break;
        __builtin_amdgcn_s_sleep(1);
      }
    }
    __syncthreads();
    asm volatile("" ::: "memory");
    const unsigned int* hc32 = hbuf32 + (t & 1) * (NB * NH / 2);
    // ---- W_h: wave = (kh, nh). A rows col & col+16, K-half kh. -----------
    {
      // issue all 32 MALL-bypass loads back-to-back (one base + imm offsets)
      const unsigned int* bp0 = hc32 + col * 512 + kh * 256 + (lane >> 4) * 4;
      const unsigned int* bp1 = bp0 + 16 * 512;
      u4 a0r[16], a1r[16];
      #define LD2(i, OFFSTR) LD16(a0r[i], bp0, OFFSTR); LD16(a1r[i], bp1, OFFSTR)
      LD2(0, "0");    LD2(1, "64");   LD2(2, "128");  LD2(3, "192");
      LD2(4, "256");  LD2(5, "320");  LD2(6, "384");  LD2(7, "448");
      LD2(8, "512");  LD2(9, "576");  LD2(10, "640"); LD2(11, "704");
      LD2(12, "768"); LD2(13, "832"); LD2(14, "896"); LD2(15, "960");
      #undef LD2
      asm volatile("s_waitcnt vmcnt(0)" ::: "memory");
      __builtin_amdgcn_sched_barrier(0);
      f4 acc[2][2] = {};
      const int koff = (lane >> 4) * 8;
      #pragma unroll
      for (int ks = 0; ks < 16; ks++) {
        int kb = kh * 512 + ks * 32 + koff;
        int n0 = nh * 32 + col, n1 = nh * 32 + 16 + col;
        sh8 b0 = *(sh8*)((char*)wlds + ((n0 * 2048 + kb * 2) ^ ((n0 & 7) << 4)));
        sh8 b1 = *(sh8*)((char*)wlds + ((n1 * 2048 + kb * 2) ^ ((n1 & 7) << 4)));
        union { u4 u; sh8 s; } A0, A1;
        A0.u = a0r[ks]; A1.u = a1r[ks];
        acc[0][0] = __builtin_amdgcn_mfma_f32_16x16x32_bf16(A0.s, b0, acc[0][0], 0, 0, 0);
        acc[0][1] = __builtin_amdgcn_mfma_f32_16x16x32_bf16(A0.s, b1, acc[0][1], 0, 0, 0);
        acc[1][0] = __builtin_amdgcn_mfma_f32_16x16x32_bf16(A1.s, b0, acc[1][0], 0, 0, 0);
        acc[1][1] = __builtin_amdgcn_mfma_f32_16x16x32_bf16(A1.s, b1, acc[1][1], 0, 0, 0);
      }
      int r0 = (lane >> 4) * 4;
      #pragma unroll
      for (int mt = 0; mt < 2; mt++)
        #pragma unroll
        for (int nt = 0; nt < 2; nt++)
          #pragma unroll
          for (int rr = 0; rr < 4; rr++)
            red[kh][mt * 16 + r0 + rr][nh * 32 + nt * 16 + col] = acc[mt][nt][rr];
    }
    __syncthreads();
    // ---- combine: thread (bq, jo2) handles jo2 and jo2+8 -----------------
    const float* zb_ = zl + bq * 48;
    #pragma unroll
    for (int half = 0; half < 2; half++) {
      int jo = jo2 + half * 8;
      float gv[4];
      #pragma unroll
      for (int g = 0; g < 4; g++) {
        float wh = red[0][bq][g * 16 + jo] + red[1][bq][g * 16 + jo];
        float dxv = 0.f, dhv = 0.f, bdv = pbbl[jo];
        #pragma unroll
        for (int e = 0; e < 4; e++) {
          dxv += zb_[g * 4 + e]      * pdl[0][e][jo];
          dhv += zb_[16 + g * 4 + e] * pdl[1][e][jo];
          bdv += zb_[32 + g * 4 + e] * pdl[2][e][jo];
        }
        gv[g] = wx[half][g] * dxv + wh * dhv + bdv;
      }
      float iv = 1.f / (1.f + __expf(-gv[0]));
      float fv = 1.f / (1.f + __expf(-gv[1]));
      float ov = 1.f / (1.f + __expf(-gv[2]));
      float gg = tanhf(gv[3]);
      int ci = bq * 16 + jo;
      float cn = fv * clds[ci] + iv * gg;
      clds[ci] = cn;
      float hn = ov * tanhf(cn);
      out[(size_t)(bq * NT + t) * NH + jh0 + jo] = hn;   // ordinary cached store
      hl16[bq][jo] = f2bf(hn);
      if (t == NT - 1) {
        out[(size_t)NB * NT * NH + bq * NH + jh0 + jo] = hn;
        out[(size_t)NB * NT * NH + NB * NH + bq * NH + jh0 + jo] = cn;
      }
    }
    __syncthreads();   // hl16 complete
    // ---- publish h(t+1): 256 x 4B MALL stores, drain, relaxed flag -------
    {
      int b = tid >> 3, p = tid & 7;
      unsigned val = (unsigned)hl16[b][2 * p] | ((unsigned)hl16[b][2 * p + 1] << 16);
      __hip_atomic_store(hbuf32 + ((t + 1) & 1) * (NB * NH / 2) + b * 512 + jw0 + p,
                         val, __ATOMIC_RELAXED, __HIP_MEMORY_SCOPE_AGENT);
    }
    asm volatile("s_waitcnt vmcnt(0)" ::: "memory");
    __syncthreads();   // all waves drained
    if (tid == 0)
      __hip_atomic_store(flags + blockIdx.x * 32, t + 1, __ATOMIC_RELAXED,
                         __HIP_MEMORY_SCOPE_AGENT);
  }
}

// ---------------------------------------------------------------------------
extern "C" void kernel_launch(void* const* d_in, const int* in_sizes, int n_in,
                              void* d_out, int out_size, void* d_ws, size_t ws_size,
                              hipStream_t stream) {
  (void)in_sizes; (void)n_in; (void)out_size;
  const float* x    = (const float*)d_in[0];
  const float* Wm   = (const float*)d_in[1];
  const float* Wih  = (const float*)d_in[2];
  const float* Wix  = (const float*)d_in[3];
  const float* bi   = (const float*)d_in[4];
  const float* Wgh  = (const float*)d_in[5];
  const float* Wgx  = (const float*)d_in[6];
  const float* bg   = (const float*)d_in[7];
  const float* Wfh  = (const float*)d_in[8];
  const float* Wfx  = (const float*)d_in[9];
  const float* bfp  = (const float*)d_in[10];
  const float* Woh  = (const float*)d_in[11];
  const float* Wox  = (const float*)d_in[12];
  const float* bo   = (const float*)d_in[13];
  const float* lnig = (const float*)d_in[14];
  const float* lnib = (const float*)d_in[15];
  const float* lngg = (const float*)d_in[16];
  const float* lngb = (const float*)d_in[17];
  const float* lnfg = (const float*)d_in[18];
  const float* lnfb = (const float*)d_in[19];
  const float* lnog = (const float*)d_in[20];
  const float* lnob = (const float*)d_in[21];
  const float* lncg = (const float*)d_in[22];
  const float* lncb = (const float*)d_in[23];
  const float* pzxw = (const float*)d_in[24];
  const float* pzxb = (const float*)d_in[25];
  const float* pzhw = (const float*)d_in[26];
  const float* pzhb = (const float*)d_in[27];
  const float* pzbw = (const float*)d_in[28];
  const float* pzbb = (const float*)d_in[29];
  const float* pdx  = (const float*)d_in[30];
  const float* pdh  = (const float*)d_in[31];
  const float* pbw  = (const float*)d_in[32];
  const float* pbb  = (const float*)d_in[33];
  float* out = (float*)d_out;

  char* ws = (char*)d_ws;
  size_t off = 0;
  auto alloc = [&](size_t bytes) {
    char* p = ws + off; off += (bytes + 255) & ~(size_t)255; return p;
  };
  unsigned short* preall = (unsigned short*)alloc((size_t)16384 * NC4 * 2);
  unsigned short* wcat   = (unsigned short*)alloc((size_t)NC4 * 512 * 2);
  unsigned short* wmht   = (unsigned short*)alloc((size_t)4096 * 1024 * 2);
  unsigned short* whht   = (unsigned short*)alloc((size_t)4 * 128 * 128 * 2);
  float* pzt             = (float*)alloc((size_t)3 * 16 * 128 * 4);
  float* zbuf            = (float*)alloc((size_t)NT * NB * 48 * 4);
  unsigned int* hbuf32   = (unsigned int*)alloc((size_t)2 * NB * NH * 2);
  int* flags             = (int*)alloc((size_t)64 * 32 * 4);
  if (off > ws_size) return;  // ws too small: leave output untouched (diagnosable)

  k_prep<<<256, 256, 0, stream>>>(Wih, Wgh, Wfh, Woh, pzxw, pzhw, pzbw, whht, pzt, hbuf32, flags);
  k_twcat<<<2304, 256, 0, stream>>>(Wm, Wix, Wgx, Wfx, Wox, wcat);
  k_twmh<<<4096, 256, 0, stream>>>(Wm, wmht);
  k_gemm<<<4608, 256, 0, stream>>>(x, wcat, preall);
  k_hyper<<<32, 512, 0, stream>>>(preall, whht, pzt, bi, bg, bfp, bo,
      lnig, lnib, lngg, lngb, lnfg, lnfb, lnog, lnob, lncg, lncb,
      pzxb, pzhb, pzbb, zbuf);
  k_main<<<NBLK, 256, 0, stream>>>(preall, wmht, zbuf, pdx, pdh, pbw, pbb, hbuf32, out, flags);
}

// Round 6
// 3995.972 us; speedup vs baseline: 2.4970x; 1.2798x over previous
//
#include <hip/hip_runtime.h>
#include <cstdint>
#include <cstddef>

#define NB 32       // batch
#define NT 512      // time steps
#define ND 512      // input dim D
#define NH 1024     // hidden H
#define NC4 4608    // 4H + 4*HH (fused GEMM N)

typedef short sh8 __attribute__((ext_vector_type(8)));   // 8 bf16 (raw bits)
typedef float f4  __attribute__((ext_vector_type(4)));
typedef unsigned int u4 __attribute__((ext_vector_type(4)));

__device__ __forceinline__ unsigned short f2bf(float x) {
  union { float f; unsigned u; } v; v.f = x;
  unsigned r = v.u + 0x7FFFu + ((v.u >> 16) & 1u);   // RNE
  return (unsigned short)(r >> 16);
}
__device__ __forceinline__ float bf2f(unsigned short b) {
  union { unsigned u; float f; } v; v.u = ((unsigned)b) << 16; return v.f;
}
__device__ __forceinline__ float blo(unsigned w) { union { unsigned u; float f; } v; v.u = w << 16; return v.f; }
__device__ __forceinline__ float bhi(unsigned w) { union { unsigned u; float f; } v; v.u = w & 0xFFFF0000u; return v.f; }

// MALL-coherent 16B load: bypasses L1/L2 (sc0 sc1).
#define LD16(dst, base, OFFSTR)                                         \
  asm volatile("global_load_dwordx4 %0, %1, off offset:" OFFSTR " sc0 sc1" \
               : "=v"(dst) : "v"(base))

// ---------------------------------------------------------------------------
// prep: hyper gate weights -> bf16 transposed [4][j=128][k=128];
//       pz weights -> fp32 [3][c=16][k=128]; zero h buf0; zero 96 flag lines
// ---------------------------------------------------------------------------
__global__ __launch_bounds__(256) void k_prep(
    const float* __restrict__ wih, const float* __restrict__ wgh,
    const float* __restrict__ wfh, const float* __restrict__ woh,
    const float* __restrict__ pzx, const float* __restrict__ pzh,
    const float* __restrict__ pzb,
    unsigned short* __restrict__ whht, float* __restrict__ pzt,
    unsigned int* __restrict__ hbuf32, int* __restrict__ flags)
{
  int idx = blockIdx.x * 256 + threadIdx.x;
  if (idx < 65536) {  // 4*128*128
    int g = idx >> 14, r = idx & 16383, j = r >> 7, k = r & 127;
    const float* w = (g == 0) ? wih : (g == 1) ? wgh : (g == 2) ? wfh : woh;
    whht[idx] = f2bf(w[k * 128 + j]);
  }
  if (idx < 6144) {   // 3*16*128
    int r = idx & 2047, c = r >> 7, k = r & 127;
    int kind = idx >> 11;
    const float* p = (kind == 0) ? pzx : (kind == 1) ? pzh : pzb;
    pzt[idx] = p[k * 16 + c];
    (void)c; (void)k;
  }
  if (idx < 16384)   // zero buf0 (32*1024 bf16) via MALL so bypass-reads see it
    __hip_atomic_store(hbuf32 + idx, 0u, __ATOMIC_RELAXED, __HIP_MEMORY_SCOPE_AGENT);
  if (idx < 3072)    // 96 flags x 32-int stride
    __hip_atomic_store(flags + idx, 0, __ATOMIC_RELAXED, __HIP_MEMORY_SCOPE_AGENT);
}

// ---------------------------------------------------------------------------
// transpose Wcat -> bf16 [n=4608][k=512]: n<4096 from Wm[:512], else Wi/g/f/o_x
// ---------------------------------------------------------------------------
__global__ __launch_bounds__(256) void k_twcat(
    const float* __restrict__ wm, const float* __restrict__ wix,
    const float* __restrict__ wgx, const float* __restrict__ wfx,
    const float* __restrict__ wox, unsigned short* __restrict__ dst)
{
  __shared__ float tile[32][33];
  int bx = blockIdx.x % 144, by = blockIdx.x / 144;
  int n0 = bx * 32, k0 = by * 32;
  int tx = threadIdx.x & 31, ty = threadIdx.x >> 5;
  #pragma unroll
  for (int i = 0; i < 4; i++) {
    int k = k0 + ty + i * 8, n = n0 + tx;
    float v;
    if (n < 4096) v = wm[(size_t)k * 4096 + n];
    else {
      int nn = n - 4096, g = nn >> 7, j = nn & 127;
      const float* w = (g == 0) ? wix : (g == 1) ? wgx : (g == 2) ? wfx : wox;
      v = w[k * 128 + j];
    }
    tile[ty + i * 8][tx] = v;
  }
  __syncthreads();
  #pragma unroll
  for (int i = 0; i < 4; i++)
    dst[(size_t)(n0 + ty + i * 8) * 512 + k0 + tx] = f2bf(tile[tx][ty + i * 8]);
}

// transpose Wm[512:] -> bf16 [n=4096][k=1024]
__global__ __launch_bounds__(256) void k_twmh(
    const float* __restrict__ wm, unsigned short* __restrict__ dst)
{
  __shared__ float tile[32][33];
  int bx = blockIdx.x % 128, by = blockIdx.x / 128;
  int n0 = bx * 32, k0 = by * 32;
  int tx = threadIdx.x & 31, ty = threadIdx.x >> 5;
  #pragma unroll
  for (int i = 0; i < 4; i++)
    tile[ty + i * 8][tx] = wm[(size_t)(512 + k0 + ty + i * 8) * 4096 + n0 + tx];
  __syncthreads();
  #pragma unroll
  for (int i = 0; i < 4; i++)
    dst[(size_t)(n0 + ty + i * 8) * 1024 + k0 + tx] = f2bf(tile[tx][ty + i * 8]);
}

// ---------------------------------------------------------------------------
// Precompute GEMM: M=16384 K=512 N=4608, bf16 MFMA, 128x128 tile, 4 waves.
// n<4096 stored block-major: n' = (jh>>4)*64 + g*16 + (jh&15)  (g=n>>10, jh=n&1023)
// so each main block's 64 gate-cols for one (t,b) are a contiguous 128B slab.
// ---------------------------------------------------------------------------
__global__ __launch_bounds__(256) void k_gemm(
    const float* __restrict__ x, const unsigned short* __restrict__ wt,
    unsigned short* __restrict__ preall)
{
  __shared__ unsigned short la[4096];  // [128 rows][32 k], XOR-swizzled 16B granules
  __shared__ unsigned short lb[4096];
  int bid = blockIdx.x;
  int mb = bid % 128, nb = bid / 128;
  int m0 = mb * 128, n0 = nb * 128;
  int tid = threadIdx.x;
  int lane = tid & 63, wid = tid >> 6;
  int wr = (wid >> 1) * 64, wc = (wid & 1) * 64;
  f4 acc[4][4] = {};
  for (int kt = 0; kt < 16; kt++) {
    int k0 = kt * 32;
    __syncthreads();
    {   // stage A (fp32 -> bf16): 2 threads/row, 16 floats each
      int r = tid >> 1, kh = (tid & 1) * 16;
      const float4* srcA = (const float4*)(x + (size_t)(m0 + r) * 512 + k0 + kh);
      unsigned pk[8];
      #pragma unroll
      for (int q = 0; q < 4; q++) {
        float4 f = srcA[q];
        pk[q * 2]     = (unsigned)f2bf(f.x) | ((unsigned)f2bf(f.y) << 16);
        pk[q * 2 + 1] = (unsigned)f2bf(f.z) | ((unsigned)f2bf(f.w) << 16);
      }
      int base = r * 64 + kh * 2;
      u4 v0 = {pk[0], pk[1], pk[2], pk[3]}, v1 = {pk[4], pk[5], pk[6], pk[7]};
      *(u4*)((char*)la + ((base)      ^ ((r & 7) << 4))) = v0;
      *(u4*)((char*)la + ((base + 16) ^ ((r & 7) << 4))) = v1;
    }
    {   // stage B (already bf16)
      int r = tid >> 1, kh = (tid & 1) * 16;
      const u4* srcB = (const u4*)(wt + (size_t)(n0 + r) * 512 + k0 + kh);
      u4 v0 = srcB[0], v1 = srcB[1];
      int base = r * 64 + kh * 2;
      *(u4*)((char*)lb + ((base)      ^ ((r & 7) << 4))) = v0;
      *(u4*)((char*)lb + ((base + 16) ^ ((r & 7) << 4))) = v1;
    }
    __syncthreads();
    int fo = (lane >> 4) * 16;
    sh8 af[4], bfr[4];
    #pragma unroll
    for (int mt = 0; mt < 4; mt++) {
      int r = wr + mt * 16 + (lane & 15);
      af[mt] = *(sh8*)((char*)la + ((r * 64 + fo) ^ ((r & 7) << 4)));
    }
    #pragma unroll
    for (int nt = 0; nt < 4; nt++) {
      int r = wc + nt * 16 + (lane & 15);
      bfr[nt] = *(sh8*)((char*)lb + ((r * 64 + fo) ^ ((r & 7) << 4)));
    }
    #pragma unroll
    for (int mt = 0; mt < 4; mt++)
      #pragma unroll
      for (int nt = 0; nt < 4; nt++)
        acc[mt][nt] = __builtin_amdgcn_mfma_f32_16x16x32_bf16(af[mt], bfr[nt], acc[mt][nt], 0, 0, 0);
  }
  #pragma unroll
  for (int mt = 0; mt < 4; mt++)
    #pragma unroll
    for (int nt = 0; nt < 4; nt++) {
      f4 a = acc[mt][nt];
      #pragma unroll
      for (int rr = 0; rr < 4; rr++) {
        int m = m0 + wr + mt * 16 + (lane >> 4) * 4 + rr;
        int n = n0 + wc + nt * 16 + (lane & 15);
        int b = m >> 9, t = m & 511;
        int nn;
        if (n < 4096) { int g = n >> 10, jh = n & 1023; nn = (jh >> 4) * 64 + g * 16 + (jh & 15); }
        else nn = n;
        preall[(size_t)(t * 32 + b) * NC4 + nn] = f2bf(a[rr]);
      }
    }
}

// ---------------------------------------------------------------------------
// Fused recurrence: 96 persistent blocks x 256 threads.
//   blocks 0..63 : main LSTM, 16 h-cols each. R4's proven flag protocol.
//   blocks 64..95: hyper LSTM, 1 batch row each; z published with same protocol.
// ---------------------------------------------------------------------------
__global__ __launch_bounds__(256) void k_rec(
    const unsigned short* __restrict__ preall,
    const unsigned short* __restrict__ wmht,
    const unsigned short* __restrict__ whht,
    const float* __restrict__ pzt,
    float* __restrict__ zbuf,             // [512][32][48] fp32
    const float* __restrict__ pdx, const float* __restrict__ pdh,
    const float* __restrict__ pbw, const float* __restrict__ pbb,
    const float* __restrict__ bi, const float* __restrict__ bg,
    const float* __restrict__ bff, const float* __restrict__ bo,
    const float* __restrict__ lnig, const float* __restrict__ lnib,
    const float* __restrict__ lngg, const float* __restrict__ lngb,
    const float* __restrict__ lnfg, const float* __restrict__ lnfb,
    const float* __restrict__ lnog, const float* __restrict__ lnob,
    const float* __restrict__ lncg, const float* __restrict__ lncb,
    const float* __restrict__ pzxb, const float* __restrict__ pzhb,
    const float* __restrict__ pzbb,
    unsigned int* __restrict__ hbuf32,    // [2][32][512] u32 (bf16 pairs) ping-pong
    float* __restrict__ out,
    int* __restrict__ flags)              // [96] x 32-int stride: 0..63 h, 64..95 z
{
  __shared__ __align__(16) unsigned short wlds[64 * 1024];   // 128KB / hyper scratch
  __shared__ float red[2][32][68];
  __shared__ __align__(16) float zl[32 * 48];
  __shared__ float clds[512];
  __shared__ __align__(16) unsigned wxl[32][32];             // [b][32 dwords] wx slab
  __shared__ float pdl[3][4][16];
  __shared__ float pbbl[16];

  const int tid = threadIdx.x;
  const int lane = tid & 63, wid = tid >> 6;

  if (blockIdx.x >= 64) {
    // =============== HYPER ROLE (b = blockIdx.x - 64) =====================
    float* const hyp  = (float*)wlds;
    float* const pzl  = hyp;          // 48*132 floats
    float* const hhs  = hyp + 6400;   // 128
    float* const chs  = hyp + 6528;   // 128
    float* const actl = hyp + 6656;   // 4*128
    float* const rwav = hyp + 7168;   // 16
    float* const redc = hyp + 7184;   // 4

    const int b = blockIdx.x - 64;
    const int j = tid & 127, gp = tid >> 7;
    const int ga = gp, gb = gp + 2;

    u4 wa[16], wb[16];
    {
      const u4* s = (const u4*)(whht + (size_t)(ga * 128 + j) * 128);
      #pragma unroll
      for (int i = 0; i < 16; i++) wa[i] = s[i];
      const u4* s2 = (const u4*)(whht + (size_t)(gb * 128 + j) * 128);
      #pragma unroll
      for (int i = 0; i < 16; i++) wb[i] = s2[i];
    }
    for (int i = tid; i < 6144; i += 256)
      pzl[(i >> 7) * 132 + (i & 127)] = pzt[i];

    const float* bias_p[4] = {bi, bg, bff, bo};
    const float* lng_p[4]  = {lnig, lngg, lnfg, lnog};
    const float* lnb_p[4]  = {lnib, lngb, lnfb, lnob};
    float bias_a = bias_p[ga][j], bias_b = bias_p[gb][j];
    float lgam_a = lng_p[ga][j],  lbet_a = lnb_p[ga][j];
    float lgam_b = lng_p[gb][j],  lbet_b = lnb_p[gb][j];
    float lcg = 0.f, lcb = 0.f;
    if (tid < 128) { lcg = lncg[j]; lcb = lncb[j]; hhs[j] = 0.f; chs[j] = 0.f; }
    float zbias = 0.f;
    if (tid < 48) {
      int kind = tid >> 4, c = tid & 15;
      zbias = ((kind == 0) ? pzxb : (kind == 1) ? pzhb : pzbb)[c];
    }
    __syncthreads();

    const f4* h4 = (const f4*)hhs;
    for (int t = 0; t < NT; t++) {
      float xa = bf2f(preall[(size_t)(t * 32 + b) * NC4 + 4096 + ga * 128 + j]);
      float xb = bf2f(preall[(size_t)(t * 32 + b) * NC4 + 4096 + gb * 128 + j]);
      float sa = bias_a, sb = bias_b;
      #pragma unroll
      for (int i = 0; i < 16; i++) {
        f4 h0 = h4[2 * i], h1 = h4[2 * i + 1];
        u4 w = wa[i];
        sa += blo(w.x) * h0[0] + bhi(w.x) * h0[1] + blo(w.y) * h0[2] + bhi(w.y) * h0[3]
            + blo(w.z) * h1[0] + bhi(w.z) * h1[1] + blo(w.w) * h1[2] + bhi(w.w) * h1[3];
        w = wb[i];
        sb += blo(w.x) * h0[0] + bhi(w.x) * h0[1] + blo(w.y) * h0[2] + bhi(w.y) * h0[3]
            + blo(w.z) * h1[0] + bhi(w.z) * h1[1] + blo(w.w) * h1[2] + bhi(w.w) * h1[3];
      }
      sa += xa; sb += xb;
      float a1 = sa, a2 = sa * sa, b1 = sb, b2 = sb * sb;
      #pragma unroll
      for (int m = 1; m < 64; m <<= 1) {
        a1 += __shfl_xor(a1, m); a2 += __shfl_xor(a2, m);
        b1 += __shfl_xor(b1, m); b2 += __shfl_xor(b2, m);
      }
      if ((tid & 63) == 0) {
        int w = tid >> 6;
        rwav[w * 4] = a1; rwav[w * 4 + 1] = a2; rwav[w * 4 + 2] = b1; rwav[w * 4 + 3] = b2;
      }
      __syncthreads();
      int w0 = gp * 2, w1 = gp * 2 + 1;
      float sum_a = rwav[w0 * 4] + rwav[w1 * 4],         sq_a = rwav[w0 * 4 + 1] + rwav[w1 * 4 + 1];
      float sum_b = rwav[w0 * 4 + 2] + rwav[w1 * 4 + 2], sq_b = rwav[w0 * 4 + 3] + rwav[w1 * 4 + 3];
      float mean_a = sum_a * 0.0078125f, var_a = sq_a * 0.0078125f - mean_a * mean_a;
      float mean_b = sum_b * 0.0078125f, var_b = sq_b * 0.0078125f - mean_b * mean_b;
      float xn_a = (sa - mean_a) * rsqrtf(var_a + 1e-5f) * lgam_a + lbet_a;
      float xn_b = (sb - mean_b) * rsqrtf(var_b + 1e-5f) * lgam_b + lbet_b;
      float act_a = (ga == 1) ? tanhf(xn_a) : 1.f / (1.f + __expf(-xn_a));
      float act_b = 1.f / (1.f + __expf(-xn_b));   // gates 2,3 sigmoid
      actl[ga * 128 + j] = act_a;
      actl[gb * 128 + j] = act_b;
      __syncthreads();
      if (tid < 128) {
        float cn = actl[2 * 128 + j] * chs[j] + actl[j] * actl[128 + j];
        chs[j] = cn;
        float c1 = cn, c2 = cn * cn;
        #pragma unroll
        for (int m = 1; m < 64; m <<= 1) { c1 += __shfl_xor(c1, m); c2 += __shfl_xor(c2, m); }
        if ((tid & 63) == 0) { int w = tid >> 6; redc[w * 2] = c1; redc[w * 2 + 1] = c2; }
      }
      __syncthreads();
      if (tid < 128) {
        float sum2 = redc[0] + redc[2], sq2 = redc[1] + redc[3];
        float mean2 = sum2 * 0.0078125f, var2 = sq2 * 0.0078125f - mean2 * mean2;
        hhs[j] = actl[3 * 128 + j] * tanhf((chs[j] - mean2) * rsqrtf(var2 + 1e-5f) * lcg + lcb);
      }
      __syncthreads();
      if (tid < 48) {   // z = hh_new @ pz*_w + pz*_b -> publish via MALL store
        const f4* pr = (const f4*)(pzl + tid * 132);
        float zv = zbias;
        #pragma unroll 8
        for (int q = 0; q < 32; q++) {
          f4 p = pr[q], hv = h4[q];
          zv += p[0] * hv[0] + p[1] * hv[1] + p[2] * hv[2] + p[3] * hv[3];
        }
        union { float f; unsigned u; } cv; cv.f = zv;
        __hip_atomic_store((unsigned*)zbuf + (size_t)(t * 32 + b) * 48 + tid, cv.u,
                           __ATOMIC_RELAXED, __HIP_MEMORY_SCOPE_AGENT);
      }
      asm volatile("s_waitcnt vmcnt(0)" ::: "memory");
      __syncthreads();   // z stores drained block-wide; also protects hhs/actl reuse
      if (tid == 0)
        __hip_atomic_store(flags + (64 + b) * 32, t + 1, __ATOMIC_RELAXED,
                           __HIP_MEMORY_SCOPE_AGENT);
    }
    return;
  }

  // ================= MAIN ROLE (blockIdx.x < 64) ==========================
  const int jh0 = blockIdx.x * 16;
  const int jw0 = blockIdx.x * 8;              // u32 col offset in hbuf32

  {   // stage weight slice once: n = g*16+jo -> wmht row g*NH + jh0 + jo
    int n = tid >> 2, kc = (tid & 3) * 256;
    int g = n >> 4, jo = n & 15;
    const unsigned short* src = wmht + (size_t)(g * NH + jh0 + jo) * NH + kc;
    #pragma unroll
    for (int i = 0; i < 32; i++) {
      sh8 v = *(const sh8*)(src + i * 8);
      int byte = n * 2048 + (kc + i * 8) * 2;
      *(sh8*)((char*)wlds + (byte ^ ((n & 7) << 4))) = v;
    }
  }
  clds[tid] = 0.f; clds[tid + 256] = 0.f;
  if (tid < 192) {
    int kind = tid >> 6, e = (tid >> 4) & 3, jo = tid & 15;
    const float* p = (kind == 0) ? pdx : (kind == 1) ? pdh : pbw;
    pdl[kind][e][jo] = p[e * NH + jh0 + jo];
  }
  if (tid < 16) pbbl[tid] = pbb[jh0 + tid];
  __syncthreads();

  const int bq = tid >> 3;      // combine row b: 0..31
  const int joB = (tid & 7) * 2; // combine adjacent col pair: joB, joB+1
  const int kh = wid >> 1, nh = wid & 1;
  const int col = lane & 15;

  for (int t = 0; t < NT; t++) {
    // ---- stage wx slab (cached, block-major preall): 256 thr x 16B -------
    {
      const u4* s = (const u4*)(preall + (size_t)(t * 32 + bq) * NC4
                                + (size_t)blockIdx.x * 64 + (tid & 7) * 8);
      *(u4*)&wxl[bq][(tid & 7) * 4] = *s;
    }
    // ---- wait for h(t) and z(t): wave0 polls h-flags + z-flags -----------
    if (wid == 0) {
      for (;;) {
        int v = (lane == blockIdx.x) ? t :
                __hip_atomic_load(flags + lane * 32, __ATOMIC_RELAXED,
                                  __HIP_MEMORY_SCOPE_AGENT);
        int ok = (v >= t);
        if (lane < 32) {
          int vz = __hip_atomic_load(flags + (64 + lane) * 32, __ATOMIC_RELAXED,
                                     __HIP_MEMORY_SCOPE_AGENT);
          ok = ok && (vz >= t + 1);
        }
        if (__all(ok)) break;
        __builtin_amdgcn_s_sleep(1);
      }
    }
    __syncthreads();
    asm volatile("" ::: "memory");
    if (tid < 192) {   // stage z(t) into LDS (data guaranteed by zflag)
      const f4* zs = (const f4*)(zbuf + (size_t)t * NB * 48) + tid * 2;
      f4 a = zs[0], bz = zs[1];
      f4* zd = (f4*)zl + tid * 2;
      zd[0] = a; zd[1] = bz;
    }
    const unsigned int* hc32 = hbuf32 + (t & 1) * (NB * NH / 2);
    // ---- W_h: wave = (kh, nh). A rows col & col+16, K-half kh. -----------
    {
      const unsigned int* bp0 = hc32 + col * 512 + kh * 256 + (lane >> 4) * 4;
      const unsigned int* bp1 = bp0 + 16 * 512;
      u4 a0r[16], a1r[16];
      #define LD2(i, OFFSTR) LD16(a0r[i], bp0, OFFSTR); LD16(a1r[i], bp1, OFFSTR)
      LD2(0, "0");    LD2(1, "64");   LD2(2, "128");  LD2(3, "192");
      LD2(4, "256");  LD2(5, "320");  LD2(6, "384");  LD2(7, "448");
      LD2(8, "512");  LD2(9, "576");  LD2(10, "640"); LD2(11, "704");
      LD2(12, "768"); LD2(13, "832"); LD2(14, "896"); LD2(15, "960");
      #undef LD2
      asm volatile("s_waitcnt vmcnt(0)" ::: "memory");
      __builtin_amdgcn_sched_barrier(0);
      f4 acc00 = {0,0,0,0}, acc01 = {0,0,0,0}, acc10 = {0,0,0,0}, acc11 = {0,0,0,0};
      const int koff = (lane >> 4) * 8;
      #pragma unroll
      for (int ks = 0; ks < 16; ks++) {
        int kb = kh * 512 + ks * 32 + koff;
        int n0 = nh * 32 + col, n1 = nh * 32 + 16 + col;
        sh8 b0 = *(sh8*)((char*)wlds + ((n0 * 2048 + kb * 2) ^ ((n0 & 7) << 4)));
        sh8 b1 = *(sh8*)((char*)wlds + ((n1 * 2048 + kb * 2) ^ ((n1 & 7) << 4)));
        union { u4 u; sh8 s; } A0, A1;
        A0.u = a0r[ks]; A1.u = a1r[ks];
        acc00 = __builtin_amdgcn_mfma_f32_16x16x32_bf16(A0.s, b0, acc00, 0, 0, 0);
        acc01 = __builtin_amdgcn_mfma_f32_16x16x32_bf16(A0.s, b1, acc01, 0, 0, 0);
        acc10 = __builtin_amdgcn_mfma_f32_16x16x32_bf16(A1.s, b0, acc10, 0, 0, 0);
        acc11 = __builtin_amdgcn_mfma_f32_16x16x32_bf16(A1.s, b1, acc11, 0, 0, 0);
      }
      int r0 = (lane >> 4) * 4;
      #pragma unroll
      for (int rr = 0; rr < 4; rr++) {
        red[kh][r0 + rr][nh * 32 + col]           = acc00[rr];
        red[kh][r0 + rr][nh * 32 + 16 + col]      = acc01[rr];
        red[kh][16 + r0 + rr][nh * 32 + col]      = acc10[rr];
        red[kh][16 + r0 + rr][nh * 32 + 16 + col] = acc11[rr];
      }
    }
    __syncthreads();
    // ---- combine: thread (bq, joB) handles adjacent jo = joB, joB+1 ------
    {
      const float* zb_ = zl + bq * 48;
      const unsigned short* wxp = (const unsigned short*)&wxl[bq][0];
      float hn2[2], cn2[2];
      #pragma unroll
      for (int half = 0; half < 2; half++) {
        int jo = joB + half;
        float gv[4];
        #pragma unroll
        for (int g = 0; g < 4; g++) {
          float wh = red[0][bq][g * 16 + jo] + red[1][bq][g * 16 + jo];
          float dxv = 0.f, dhv = 0.f, bdv = pbbl[jo];
          #pragma unroll
          for (int e = 0; e < 4; e++) {
            dxv += zb_[g * 4 + e]      * pdl[0][e][jo];
            dhv += zb_[16 + g * 4 + e] * pdl[1][e][jo];
            bdv += zb_[32 + g * 4 + e] * pdl[2][e][jo];
          }
          float wxv = bf2f(wxp[g * 16 + jo]);
          gv[g] = wxv * dxv + wh * dhv + bdv;
        }
        float iv = 1.f / (1.f + __expf(-gv[0]));
        float fv = 1.f / (1.f + __expf(-gv[1]));
        float ov = 1.f / (1.f + __expf(-gv[2]));
        float gg = tanhf(gv[3]);
        int ci = bq * 16 + jo;
        float cn = fv * clds[ci] + iv * gg;
        clds[ci] = cn;
        hn2[half] = ov * tanhf(cn);
        cn2[half] = cn;
      }
      *(float2*)&out[(size_t)(bq * NT + t) * NH + jh0 + joB] = make_float2(hn2[0], hn2[1]);
      unsigned val = (unsigned)f2bf(hn2[0]) | ((unsigned)f2bf(hn2[1]) << 16);
      __hip_atomic_store(hbuf32 + ((t + 1) & 1) * (NB * NH / 2) + bq * 512 + jw0 + (joB >> 1),
                         val, __ATOMIC_RELAXED, __HIP_MEMORY_SCOPE_AGENT);
      if (t == NT - 1) {
        *(float2*)&out[(size_t)NB * NT * NH + bq * NH + jh0 + joB] = make_float2(hn2[0], hn2[1]);
        *(float2*)&out[(size_t)NB * NT * NH + NB * NH + bq * NH + jh0 + joB] = make_float2(cn2[0], cn2[1]);
      }
    }
    // ---- publish flag after all h stores drained -------------------------
    asm volatile("s_waitcnt vmcnt(0)" ::: "memory");
    __syncthreads();   // all waves drained; also protects red/zl/wxl/clds
    if (tid == 0)
      __hip_atomic_store(flags + blockIdx.x * 32, t + 1, __ATOMIC_RELAXED,
                         __HIP_MEMORY_SCOPE_AGENT);
  }
}

// ---------------------------------------------------------------------------
extern "C" void kernel_launch(void* const* d_in, const int* in_sizes, int n_in,
                              void* d_out, int out_size, void* d_ws, size_t ws_size,
                              hipStream_t stream) {
  (void)in_sizes; (void)n_in; (void)out_size;
  const float* x    = (const float*)d_in[0];
  const float* Wm   = (const float*)d_in[1];
  const float* Wih  = (const float*)d_in[2];
  const float* Wix  = (const float*)d_in[3];
  const float* bi   = (const float*)d_in[4];
  const float* Wgh  = (const float*)d_in[5];
  const float* Wgx  = (const float*)d_in[6];
  const float* bg   = (const float*)d_in[7];
  const float* Wfh  = (const float*)d_in[8];
  const float* Wfx  = (const float*)d_in[9];
  const float* bfp  = (const float*)d_in[10];
  const float* Woh  = (const float*)d_in[11];
  const float* Wox  = (const float*)d_in[12];
  const float* bo   = (const float*)d_in[13];
  const float* lnig = (const float*)d_in[14];
  const float* lnib = (const float*)d_in[15];
  const float* lngg = (const float*)d_in[16];
  const float* lngb = (const float*)d_in[17];
  const float* lnfg = (const float*)d_in[18];
  const float* lnfb = (const float*)d_in[19];
  const float* lnog = (const float*)d_in[20];
  const float* lnob = (const float*)d_in[21];
  const float* lncg = (const float*)d_in[22];
  const float* lncb = (const float*)d_in[23];
  const float* pzxw = (const float*)d_in[24];
  const float* pzxb = (const float*)d_in[25];
  const float* pzhw = (const float*)d_in[26];
  const float* pzhb = (const float*)d_in[27];
  const float* pzbw = (const float*)d_in[28];
  const float* pzbb = (const float*)d_in[29];
  const float* pdx  = (const float*)d_in[30];
  const float* pdh  = (const float*)d_in[31];
  const float* pbw  = (const float*)d_in[32];
  const float* pbb  = (const float*)d_in[33];
  float* out = (float*)d_out;

  char* ws = (char*)d_ws;
  size_t off = 0;
  auto alloc = [&](size_t bytes) {
    char* p = ws + off; off += (bytes + 255) & ~(size_t)255; return p;
  };
  unsigned short* preall = (unsigned short*)alloc((size_t)16384 * NC4 * 2);
  unsigned short* wcat   = (unsigned short*)alloc((size_t)NC4 * 512 * 2);
  unsigned short* wmht   = (unsigned short*)alloc((size_t)4096 * 1024 * 2);
  unsigned short* whht   = (unsigned short*)alloc((size_t)4 * 128 * 128 * 2);
  float* pzt             = (float*)alloc((size_t)3 * 16 * 128 * 4);
  float* zbuf            = (float*)alloc((size_t)NT * NB * 48 * 4);
  unsigned int* hbuf32   = (unsigned int*)alloc((size_t)2 * NB * NH * 2);
  int* flags             = (int*)alloc((size_t)96 * 32 * 4);
  if (off > ws_size) return;  // ws too small: leave output untouched (diagnosable)

  k_prep<<<256, 256, 0, stream>>>(Wih, Wgh, Wfh, Woh, pzxw, pzhw, pzbw, whht, pzt, hbuf32, flags);
  k_twcat<<<2304, 256, 0, stream>>>(Wm, Wix, Wgx, Wfx, Wox, wcat);
  k_twmh<<<4096, 256, 0, stream>>>(Wm, wmht);
  k_gemm<<<4608, 256, 0, stream>>>(x, wcat, preall);
  k_rec<<<96, 256, 0, stream>>>(preall, wmht, whht, pzt, zbuf,
      pdx, pdh, pbw, pbb, bi, bg, bfp, bo,
      lnig, lnib, lngg, lngb, lnfg, lnfb, lnog, lnob, lncg, lncb,
      pzxb, pzhb, pzbb, hbuf32, out, flags);
}